// Round 14
// baseline (858.144 us; speedup 1.0000x reference)
//
#include <hip/hip_runtime.h>

#define NN   729
#define NF   730   // N+1
#define BV   8
#define KK   32
#define NBAS 40
#define MAXIT 10
#define PI_F 3.14159265358979323846f

#define MTH   512   // mix threads (8 waves; 512-thr kernels get ~124 VGPR budget)
#define BT    16    // steps per block
#define AST   448   // padded max active rows; CactT stride

typedef float v2f __attribute__((ext_vector_type(2)));

__device__ __forceinline__ void fma4(float4& w, float c, const float4& d) {
    w.x = fmaf(c, d.x, w.x); w.y = fmaf(c, d.y, w.y);
    w.z = fmaf(c, d.z, w.z); w.w = fmaf(c, d.w, w.w);
}

// ---------------- build Ct (730x730), Ct[i][j] = C[j][i] ----------------
__global__ void build_C_kernel(const float* __restrict__ coeff,
                               const float* __restrict__ upper,
                               const float* __restrict__ basis,
                               float* __restrict__ Ct) {
    int idx = blockIdx.x * blockDim.x + threadIdx.x;
    if (idx >= NF * NF) return;
    int i = idx / NF, j = idx - i * NF;
    float val;
    if (i == 0) {
        val = (j == 0) ? 0.f : upper[j - 1];
    } else if (j == 0) {
        val = upper[i - 1];
    } else {
        float acc = 0.f;
        const float* bp = basis + (size_t)(i - 1) * NN + (j - 1);
        #pragma unroll 8
        for (int b = 0; b < NBAS; ++b)
            acc = fmaf(coeff[b], bp[(size_t)b * NN * NN], acc);
        val = acc;
    }
    Ct[(size_t)j * NF + i] = val;
}

// ---------------- init V  (B x 730 x 32) ----------------
__global__ void init_V_kernel(const float* __restrict__ z,
                              const float* __restrict__ vraw,
                              float* __restrict__ V) {
    int g = threadIdx.x >> 5;
    int k = threadIdx.x & 31;
    int row = blockIdx.x * 8 + g;           // 0..5839
    int b = row / NF, n = row - b * NF;
    const float* vr = vraw + (size_t)b * NF * KK;

    float v0 = vr[k];
    float s2 = v0 * v0;
    #pragma unroll
    for (int off = 16; off; off >>= 1) s2 += __shfl_xor(s2, off, 32);
    v0 = v0 / sqrtf(s2);

    float vn = vr[(size_t)n * KK + k];
    float d = vn * v0;
    #pragma unroll
    for (int off = 16; off; off >>= 1) d += __shfl_xor(d, off, 32);
    float u = vn - d * v0;
    float un2 = u * u;
    #pragma unroll
    for (int off = 16; off; off >>= 1) un2 += __shfl_xor(un2, off, 32);
    u = u / fmaxf(sqrtf(un2), 1e-8f);

    float zf = (n == 0) ? 1.f : z[b * NN + (n - 1)];
    float c = cosf(PI_F * zf), s = sinf(PI_F * zf);
    float outv = -c * v0 + s * u;
    if (n == 0) outv = v0;
    V[((size_t)b * NF + n) * KK + k] = outv;
}

// ---------------- build per-batch active lists (perm order) ----------------
__global__ void build_act_kernel(const int* __restrict__ is_input,
                                 const int* __restrict__ perm,
                                 int* __restrict__ act, int* __restrict__ nA_arr) {
    int b = blockIdx.x, l = threadIdx.x;   // 64 threads = 1 wave
    int base = 0;
    for (int c = 0; c < (NN + 63) / 64; ++c) {
        int idx = c * 64 + l;
        bool f = false; int pi = 0;
        if (idx < NN) { pi = perm[idx]; f = (is_input[b * NN + pi - 1] == 0); }
        unsigned long long m = __ballot(f);
        int pos = __popcll(m & ((1ull << l) - 1ull));
        if (f && base + pos < AST) act[b * AST + base + pos] = pi;
        base += __popcll(m);
    }
    if (base > AST) base = AST;
    if (l == 0) nA_arr[b] = base;
    for (int p = base + l; p < AST; p += 64) act[b * AST + p] = 0;
}

// --- gather CactT[b][a][t] = C[r_t][r_a] = Ct[r_a][r_t] (row-coalesced) ---
__global__ void gather_CactT_kernel(const float* __restrict__ Ct,
                                    const int* __restrict__ act,
                                    float* __restrict__ CactT) {
    int a = blockIdx.x, b = blockIdx.y;
    __shared__ int acts[AST];
    for (int i = threadIdx.x; i < AST; i += blockDim.x) acts[i] = act[b * AST + i];
    __syncthreads();
    const float* src = Ct + (size_t)acts[a] * NF;
    float* dst = CactT + ((size_t)b * AST + a) * AST;
    for (int t = threadIdx.x; t < AST; t += blockDim.x)
        dst[t] = src[acts[t]];
}

// --- init W compact + compact V copy ---
__global__ void init_W_kernel(const float* __restrict__ Ct,
                              const int* __restrict__ act,
                              const int* __restrict__ nA_arr,
                              const float* __restrict__ V,
                              float* __restrict__ Wc,
                              float* __restrict__ Vact) {
    int b = blockIdx.y;
    int a = blockIdx.x * 8 + (threadIdx.x >> 5);
    int k = threadIdx.x & 31;
    int nA = nA_arr[b];
    float w = 0.f;
    int ra = act[b * AST + a];
    float vv = V[((size_t)b * NF + ra) * KK + k];
    if (a < nA) {
        const float* ctr = Ct + (size_t)ra * NF;
        const float* vb = V + (size_t)b * NF * KK + k;
        float acc = 0.f;
        for (int j = 0; j < NF; ++j)
            acc = fmaf(ctr[j], vb[(size_t)j * KK], acc);
        w = acc - ctr[ra] * vv;
    }
    Wc[((size_t)b * AST + a) * KK + k] = w;
    Vact[((size_t)b * AST + a) * KK + k] = vv;
}

// 16-lane row sum via DPP row rotations (pure VALU)
__device__ __forceinline__ float rowsum16(float x) {
    int y;
    y = __builtin_amdgcn_update_dpp(0, __float_as_int(x), 0x121, 0xF, 0xF, false);
    x += __int_as_float(y);
    y = __builtin_amdgcn_update_dpp(0, __float_as_int(x), 0x122, 0xF, 0xF, false);
    x += __int_as_float(y);
    y = __builtin_amdgcn_update_dpp(0, __float_as_int(x), 0x124, 0xF, 0xF, false);
    x += __int_as_float(y);
    y = __builtin_amdgcn_update_dpp(0, __float_as_int(x), 0x128, 0xF, 0xF, false);
    x += __int_as_float(y);
    return x;
}

// -- mixing: single barrier/iter; W in bulk regs; serial folds cmini itself --
__global__ __launch_bounds__(MTH, 2)
void mix_kernel(const float* __restrict__ CactT_g,
                const float* __restrict__ Wc_g,
                const float* __restrict__ Vact_g,
                const int* __restrict__ act_g,
                const int* __restrict__ nA_arr,
                const int* __restrict__ is_input,
                const float* __restrict__ z,
                const float* __restrict__ Vg,
                float* __restrict__ out) {
    __shared__ __align__(16) float V_c[AST * KK];        // 57344 B
    __shared__ __align__(16) float dv_s[2][BT * KK];     // 4096 B
    __shared__ __align__(16) float gpub[2][BT * KK];     // 4096 B
    __shared__ __align__(16) float cblk_s[2][BT * BT];   // 2048 B
    __shared__ __align__(16) float cminiT_s[2][BT * BT]; // 2048 B
    __shared__ float Cd_s[AST];                          // 1792 B
    __shared__ int   slot_s[NF];                         // 2920 B

    int b = blockIdx.x, tid = threadIdx.x;
    const float* CT = CactT_g + (size_t)b * AST * AST;
    const float* Vact = Vact_g + (size_t)b * AST * KK;
    int nA = nA_arr[b];
    int nblkp = (nA + BT - 1) / BT;
    if (nblkp < 2) nblkp = 2;
    int nAp = nblkp * BT;
    int totB = MAXIT * nblkp;

    int wid = tid >> 6;
    int l64 = tid & 63;
    int lane = tid - 64;          // bulk lane 0..447 (valid when wid>=1)
    int kq = lane & 7;            // k-quad: floats 4kq..4kq+3
    int rslot = lane >> 3;        // 0..55; rows rslot + 56p
    int kp = tid & 15;            // serial k-pair

    // ---- setup ----
    for (int idx = tid; idx < AST * 8; idx += MTH)
        ((float4*)V_c)[idx] = ((const float4*)Vact)[idx];
    if (tid < AST) Cd_s[tid] = CT[(size_t)tid * AST + tid];
    if (tid < nA) slot_s[act_g[b * AST + tid]] = tid;
    if (tid < 256) {   // cblk for block 0: cblk[x][y] = C[r_x][r_y]
        int t = tid >> 4, u = tid & 15;
        cblk_s[0][t * BT + u] = CT[(size_t)u * AST + t];
    }
    // W rows into registers
    float4 w[8];
    #pragma unroll
    for (int p = 0; p < 8; ++p) {
        float4 zz = {0.f, 0.f, 0.f, 0.f};
        w[p] = zz;
        if (wid >= 1)
            w[p] = *(const float4*)&Wc_g[((size_t)b * AST + rslot + 56 * p) * KK + 4 * kq];
    }
    // initial gpub for block 0 (read by serial at bi=0 from gpub[1])
    if (wid >= 1) {
        #pragma unroll
        for (int p = 0; p < 8; ++p) {
            int a = rslot + 56 * p;
            if ((a >> 4) == 0)
                *(float4*)&gpub[1][a * KK + 4 * kq] = w[p];
        }
    }
    __syncthreads();

    for (int bi = 0; bi < totB; ++bi) {
        int blk = bi % nblkp, s0 = blk * BT;
        int pblk = (bi - 1 + nblkp) % nblkp, sp0 = pblk * BT;  // junk at bi=0
        int cb = bi & 1, pv = cb ^ 1;
        int nblk2 = (bi + 1) % nblkp, sn0 = nblk2 * BT;

        if (wid == 0) {
            // ---- serial: gpub + cmini correction + 16-step chain ----
            float g0[BT], g1[BT], vo0[BT], vo1[BT];
            #pragma unroll
            for (int u = 0; u < BT; ++u) {
                v2f gv = *(const v2f*)&gpub[pv][u * KK + 2 * kp];
                g0[u] = gv.x; g1[u] = gv.y;
                v2f vv = *(const v2f*)&V_c[(s0 + u) * KK + 2 * kp];
                vo0[u] = vv.x; vo1[u] = vv.y;
            }
            if (bi > 0) {   // fold in dv(bi-1): g[u] += cminiT[t][u]*dvp[t]
                #pragma unroll
                for (int t = 0; t < BT; ++t) {
                    v2f dp = *(const v2f*)&dv_s[pv][t * KK + 2 * kp];
                    #pragma unroll
                    for (int q = 0; q < 4; ++q) {
                        float4 cm = *(const float4*)&cminiT_s[cb][t * BT + 4 * q];
                        g0[4*q+0] = fmaf(cm.x, dp.x, g0[4*q+0]);
                        g1[4*q+0] = fmaf(cm.x, dp.y, g1[4*q+0]);
                        g0[4*q+1] = fmaf(cm.y, dp.x, g0[4*q+1]);
                        g1[4*q+1] = fmaf(cm.y, dp.y, g1[4*q+1]);
                        g0[4*q+2] = fmaf(cm.z, dp.x, g0[4*q+2]);
                        g1[4*q+2] = fmaf(cm.z, dp.y, g1[4*q+2]);
                        g0[4*q+3] = fmaf(cm.w, dp.x, g0[4*q+3]);
                        g1[4*q+3] = fmaf(cm.w, dp.y, g1[4*q+3]);
                    }
                }
            }
            #pragma unroll
            for (int u = 0; u < BT; ++u) {
                int s = s0 + u;
                float n2 = fmaf(g0[u], g0[u], g1[u] * g1[u]);
                n2 = rowsum16(n2);
                float inv = -__builtin_amdgcn_rsqf(fmaxf(n2, 1e-16f));
                float msk = (s < nA) ? 1.f : 0.f;
                float d0 = fmaf(g0[u], inv, -vo0[u]) * msk;
                float d1 = fmaf(g1[u], inv, -vo1[u]) * msk;
                if (tid < 16) {
                    v2f dv2; dv2.x = d0; dv2.y = d1;
                    *(v2f*)&dv_s[cb][u * KK + 2 * kp] = dv2;
                    v2f vn2; vn2.x = vo0[u] + d0; vn2.y = vo1[u] + d1;
                    *(v2f*)&V_c[s * KK + 2 * kp] = vn2;
                }
                #pragma unroll
                for (int u2 = u + 1; u2 < BT; ++u2) {
                    float c = cblk_s[cb][u * BT + u2];
                    g0[u2] = fmaf(c, d0, g0[u2]);
                    g1[u2] = fmaf(c, d1, g1[u2]);
                }
            }
        } else {
            if (wid == 6) {   // cminiT[pv][t*16+u] = C[r_{s0+t}][r_{sn0+u}]
                int u = l64 & 15, q = l64 >> 4;
                float4 v = *(const float4*)&CT[(size_t)(sn0 + u) * AST + s0 + 4 * q];
                cminiT_s[pv][(4 * q + 0) * BT + u] = v.x;
                cminiT_s[pv][(4 * q + 1) * BT + u] = v.y;
                cminiT_s[pv][(4 * q + 2) * BT + u] = v.z;
                cminiT_s[pv][(4 * q + 3) * BT + u] = v.w;
            }
            if (wid == 7) {   // cblk[pv]: next block's intra tile (transposed)
                int u = l64 & 15, q = l64 >> 4;
                float4 v = *(const float4*)&CT[(size_t)(sn0 + u) * AST + sn0 + 4 * q];
                cblk_s[pv][(4 * q + 0) * BT + u] = v.x;
                cblk_s[pv][(4 * q + 1) * BT + u] = v.y;
                cblk_s[pv][(4 * q + 2) * BT + u] = v.z;
                cblk_s[pv][(4 * q + 3) * BT + u] = v.w;
            }
            // ---- bulk: rank-16 (ALL rows) in two rank-8 halves ----
            if (bi > 0) {
                #pragma unroll
                for (int h = 0; h < 2; ++h) {
                    float4 dvv[8];
                    #pragma unroll
                    for (int t = 0; t < 8; ++t)
                        dvv[t] = *(const float4*)&dv_s[pv][(8 * h + t) * KK + 4 * kq];
                    float4 cA0, cB0, cA1, cB1;
                    {
                        const float* cr = CT + (size_t)rslot * AST + sp0 + 8 * h;
                        cA0 = *(const float4*)(cr);
                        cB0 = *(const float4*)(cr + 4);
                    }
                    #pragma unroll
                    for (int p = 0; p < 8; ++p) {
                        int a = rslot + 56 * p;
                        if (p < 7) {   // prefetch next pass's c
                            const float* cr = CT + (size_t)(a + 56) * AST + sp0 + 8 * h;
                            if (p & 1) { cA0 = *(const float4*)(cr); cB0 = *(const float4*)(cr + 4); }
                            else       { cA1 = *(const float4*)(cr); cB1 = *(const float4*)(cr + 4); }
                        }
                        float4 ca = (p & 1) ? cA1 : cA0;
                        float4 cbq = (p & 1) ? cB1 : cB0;
                        if (a < nAp) {
                            fma4(w[p], ca.x,  dvv[0]);
                            fma4(w[p], ca.y,  dvv[1]);
                            fma4(w[p], ca.z,  dvv[2]);
                            fma4(w[p], ca.w,  dvv[3]);
                            fma4(w[p], cbq.x, dvv[4]);
                            fma4(w[p], cbq.y, dvv[5]);
                            fma4(w[p], cbq.z, dvv[6]);
                            fma4(w[p], cbq.w, dvv[7]);
                        }
                    }
                }
                // diag self-cancel for rows of the previous block
                #pragma unroll
                for (int p = 0; p < 8; ++p) {
                    int a = rslot + 56 * p;
                    if ((a >> 4) == pblk) {
                        float4 dd = *(const float4*)&dv_s[pv][(a - sp0) * KK + 4 * kq];
                        fma4(w[p], -Cd_s[a], dd);
                    }
                }
            }
            // ---- publish next block's rows (after all updates this iter) ----
            #pragma unroll
            for (int p = 0; p < 8; ++p) {
                int a = rslot + 56 * p;
                if ((a >> 4) == nblk2)
                    *(float4*)&gpub[cb][(a - sn0) * KK + 4 * kq] = w[p];
            }
        }
        __syncthreads();
    }

    // ---- epilogue: z_out ----
    int k = tid & 31, r = tid >> 5;   // r in 0..15
    float v0k = Vg[(size_t)b * NF * KK + k];
    for (int n = 1 + r; n <= NN; n += 16) {
        int ii = is_input[b * NN + n - 1];
        float res;
        if (ii == 1) {
            res = z[b * NN + n - 1];
        } else {
            int a = slot_s[n];
            float dot = V_c[a * KK + k] * v0k;
            #pragma unroll
            for (int off = 16; off; off >>= 1) dot += __shfl_xor(dot, off, 32);
            float ca = fminf(fmaxf(-dot, -1.f + 1e-6f), 1.f - 1e-6f);
            res = acosf(ca) * (1.f / PI_F);
        }
        if (k == 0) out[b * NN + n - 1] = res;
    }
}

extern "C" void kernel_launch(void* const* d_in, const int* in_sizes, int n_in,
                              void* d_out, int out_size, void* d_ws, size_t ws_size,
                              hipStream_t stream) {
    const float* coeff    = (const float*)d_in[0];
    const float* upper    = (const float*)d_in[1];
    const float* basis    = (const float*)d_in[2];
    const float* z        = (const float*)d_in[3];
    const int*   is_input = (const int*)d_in[4];
    const float* vraw     = (const float*)d_in[5];
    const int*   perm     = (const int*)d_in[6];
    float* out = (float*)d_out;

    float* ws    = (float*)d_ws;
    float* Ct    = ws;                               // 730*730
    float* V     = Ct + (size_t)NF * NF;             // 8*730*32
    float* CactT = V + (size_t)BV * NF * KK;         // 8*448*448
    float* Wc    = CactT + (size_t)BV * AST * AST;   // 8*448*32
    float* Vact  = Wc + (size_t)BV * AST * KK;       // 8*448*32
    int*   act   = (int*)(Vact + (size_t)BV * AST * KK);  // 8*448
    int*   nAa   = act + BV * AST;                   // 8
    // total ws ≈ 10.3 MB

    build_C_kernel<<<dim3((NF * NF + 255) / 256), dim3(256), 0, stream>>>(coeff, upper, basis, Ct);
    init_V_kernel<<<dim3(730), dim3(256), 0, stream>>>(z, vraw, V);
    build_act_kernel<<<dim3(BV), dim3(64), 0, stream>>>(is_input, perm, act, nAa);
    gather_CactT_kernel<<<dim3(AST, BV), dim3(256), 0, stream>>>(Ct, act, CactT);
    init_W_kernel<<<dim3(AST / 8, BV), dim3(256), 0, stream>>>(Ct, act, nAa, V, Wc, Vact);
    mix_kernel<<<dim3(BV), dim3(MTH), 0, stream>>>(CactT, Wc, Vact, act, nAa, is_input, z, V, out);
}

// Round 15
// 743.646 us; speedup vs baseline: 1.1540x; 1.1540x over previous
//
#include <hip/hip_runtime.h>

#define NN   729
#define NF   730   // N+1
#define BV   8
#define KK   32
#define NBAS 40
#define MAXIT 10
#define PI_F 3.14159265358979323846f

#define MTH   512   // mix threads (8 waves; 512-thr kernels get ~124 VGPR budget)
#define BT    16    // steps per block
#define AST   448   // padded max active rows; CactT stride

typedef float v2f __attribute__((ext_vector_type(2)));

__device__ __forceinline__ void fma4(float4& w, float c, const float4& d) {
    w.x = fmaf(c, d.x, w.x); w.y = fmaf(c, d.y, w.y);
    w.z = fmaf(c, d.z, w.z); w.w = fmaf(c, d.w, w.w);
}

// ---------------- build Ct (730x730), Ct[i][j] = C[j][i] ----------------
__global__ void build_C_kernel(const float* __restrict__ coeff,
                               const float* __restrict__ upper,
                               const float* __restrict__ basis,
                               float* __restrict__ Ct) {
    int idx = blockIdx.x * blockDim.x + threadIdx.x;
    if (idx >= NF * NF) return;
    int i = idx / NF, j = idx - i * NF;
    float val;
    if (i == 0) {
        val = (j == 0) ? 0.f : upper[j - 1];
    } else if (j == 0) {
        val = upper[i - 1];
    } else {
        float acc = 0.f;
        const float* bp = basis + (size_t)(i - 1) * NN + (j - 1);
        #pragma unroll 8
        for (int b = 0; b < NBAS; ++b)
            acc = fmaf(coeff[b], bp[(size_t)b * NN * NN], acc);
        val = acc;
    }
    Ct[(size_t)j * NF + i] = val;
}

// ---------------- init V  (B x 730 x 32) ----------------
__global__ void init_V_kernel(const float* __restrict__ z,
                              const float* __restrict__ vraw,
                              float* __restrict__ V) {
    int g = threadIdx.x >> 5;
    int k = threadIdx.x & 31;
    int row = blockIdx.x * 8 + g;           // 0..5839
    int b = row / NF, n = row - b * NF;
    const float* vr = vraw + (size_t)b * NF * KK;

    float v0 = vr[k];
    float s2 = v0 * v0;
    #pragma unroll
    for (int off = 16; off; off >>= 1) s2 += __shfl_xor(s2, off, 32);
    v0 = v0 / sqrtf(s2);

    float vn = vr[(size_t)n * KK + k];
    float d = vn * v0;
    #pragma unroll
    for (int off = 16; off; off >>= 1) d += __shfl_xor(d, off, 32);
    float u = vn - d * v0;
    float un2 = u * u;
    #pragma unroll
    for (int off = 16; off; off >>= 1) un2 += __shfl_xor(un2, off, 32);
    u = u / fmaxf(sqrtf(un2), 1e-8f);

    float zf = (n == 0) ? 1.f : z[b * NN + (n - 1)];
    float c = cosf(PI_F * zf), s = sinf(PI_F * zf);
    float outv = -c * v0 + s * u;
    if (n == 0) outv = v0;
    V[((size_t)b * NF + n) * KK + k] = outv;
}

// ---------------- build per-batch active lists (perm order) ----------------
__global__ void build_act_kernel(const int* __restrict__ is_input,
                                 const int* __restrict__ perm,
                                 int* __restrict__ act, int* __restrict__ nA_arr) {
    int b = blockIdx.x, l = threadIdx.x;   // 64 threads = 1 wave
    int base = 0;
    for (int c = 0; c < (NN + 63) / 64; ++c) {
        int idx = c * 64 + l;
        bool f = false; int pi = 0;
        if (idx < NN) { pi = perm[idx]; f = (is_input[b * NN + pi - 1] == 0); }
        unsigned long long m = __ballot(f);
        int pos = __popcll(m & ((1ull << l) - 1ull));
        if (f && base + pos < AST) act[b * AST + base + pos] = pi;
        base += __popcll(m);
    }
    if (base > AST) base = AST;
    if (l == 0) nA_arr[b] = base;
    for (int p = base + l; p < AST; p += 64) act[b * AST + p] = 0;
}

// --- gather CactT[b][a][t] = C[r_t][r_a] = Ct[r_a][r_t] (row-coalesced) ---
__global__ void gather_CactT_kernel(const float* __restrict__ Ct,
                                    const int* __restrict__ act,
                                    float* __restrict__ CactT) {
    int a = blockIdx.x, b = blockIdx.y;
    __shared__ int acts[AST];
    for (int i = threadIdx.x; i < AST; i += blockDim.x) acts[i] = act[b * AST + i];
    __syncthreads();
    const float* src = Ct + (size_t)acts[a] * NF;
    float* dst = CactT + ((size_t)b * AST + a) * AST;
    for (int t = threadIdx.x; t < AST; t += blockDim.x)
        dst[t] = src[acts[t]];
}

// --- init W compact + compact V copy ---
__global__ void init_W_kernel(const float* __restrict__ Ct,
                              const int* __restrict__ act,
                              const int* __restrict__ nA_arr,
                              const float* __restrict__ V,
                              float* __restrict__ Wc,
                              float* __restrict__ Vact) {
    int b = blockIdx.y;
    int a = blockIdx.x * 8 + (threadIdx.x >> 5);
    int k = threadIdx.x & 31;
    int nA = nA_arr[b];
    float w = 0.f;
    int ra = act[b * AST + a];
    float vv = V[((size_t)b * NF + ra) * KK + k];
    if (a < nA) {
        const float* ctr = Ct + (size_t)ra * NF;
        const float* vb = V + (size_t)b * NF * KK + k;
        float acc = 0.f;
        for (int j = 0; j < NF; ++j)
            acc = fmaf(ctr[j], vb[(size_t)j * KK], acc);
        w = acc - ctr[ra] * vv;
    }
    Wc[((size_t)b * AST + a) * KK + k] = w;
    Vact[((size_t)b * AST + a) * KK + k] = vv;
}

// 16-lane row sum via DPP row rotations (pure VALU)
__device__ __forceinline__ float rowsum16(float x) {
    int y;
    y = __builtin_amdgcn_update_dpp(0, __float_as_int(x), 0x121, 0xF, 0xF, false);
    x += __int_as_float(y);
    y = __builtin_amdgcn_update_dpp(0, __float_as_int(x), 0x122, 0xF, 0xF, false);
    x += __int_as_float(y);
    y = __builtin_amdgcn_update_dpp(0, __float_as_int(x), 0x124, 0xF, 0xF, false);
    x += __int_as_float(y);
    y = __builtin_amdgcn_update_dpp(0, __float_as_int(x), 0x128, 0xF, 0xF, false);
    x += __int_as_float(y);
    return x;
}

// -- mixing: R1 = serial || full bulk; R2 = thin cooperative gpub fold --
__global__ __launch_bounds__(MTH, 2)
void mix_kernel(const float* __restrict__ CactT_g,
                const float* __restrict__ Wc_g,
                const float* __restrict__ Vact_g,
                const int* __restrict__ act_g,
                const int* __restrict__ nA_arr,
                const int* __restrict__ is_input,
                const float* __restrict__ z,
                const float* __restrict__ Vg,
                float* __restrict__ out) {
    __shared__ __align__(16) float V_c[AST * KK];       // 57344 B
    __shared__ __align__(16) float dv_s[2][BT * KK];    // 4096 B
    __shared__ __align__(16) float gpub[2][BT * KK];    // 4096 B
    __shared__ __align__(16) float cblk_s[2][BT * BT];  // 2048 B
    __shared__ __align__(16) float cmini_s[BT * BT];    // 1024 B
    __shared__ float Cd_s[AST];                         // 1792 B
    __shared__ int   slot_s[NF];                        // 2920 B

    int b = blockIdx.x, tid = threadIdx.x;
    const float* CT = CactT_g + (size_t)b * AST * AST;
    const float* Vact = Vact_g + (size_t)b * AST * KK;
    int nA = nA_arr[b];
    int nblkp = (nA + BT - 1) / BT;
    if (nblkp < 2) nblkp = 2;
    int nAp = nblkp * BT;
    int totB = MAXIT * nblkp;

    int wid = tid >> 6;
    int l64 = tid & 63;
    int lane = tid - 64;          // bulk lane 0..447 (valid when wid>=1)
    int kq = lane & 7;            // k-quad: floats 4kq..4kq+3
    int rslot = lane >> 3;        // 0..55; rows rslot + 56p
    int kp = tid & 15;            // serial k-pair

    // ---- setup ----
    for (int idx = tid; idx < AST * 8; idx += MTH)
        ((float4*)V_c)[idx] = ((const float4*)Vact)[idx];
    if (tid < AST) Cd_s[tid] = CT[(size_t)tid * AST + tid];
    if (tid < nA) slot_s[act_g[b * AST + tid]] = tid;
    if (tid < 256) {   // cblk for block 0: cblk[x][y] = C[r_x][r_y]
        int t = tid >> 4, u = tid & 15;
        cblk_s[0][t * BT + u] = CT[(size_t)u * AST + t];
    }
    // W rows into registers
    float4 w[8];
    #pragma unroll
    for (int p = 0; p < 8; ++p) {
        float4 zz = {0.f, 0.f, 0.f, 0.f};
        w[p] = zz;
        if (wid >= 1)
            w[p] = *(const float4*)&Wc_g[((size_t)b * AST + rslot + 56 * p) * KK + 4 * kq];
    }
    // publish block-0 rows (no prior dv) into gpub[1] (pv at bi=0)
    if (wid >= 1) {
        #pragma unroll
        for (int p = 0; p < 8; ++p) {
            int a = rslot + 56 * p;
            if ((a >> 4) == 0)
                *(float4*)&gpub[1][a * KK + 4 * kq] = w[p];
        }
    }
    __syncthreads();

    for (int bi = 0; bi < totB; ++bi) {
        int blk = bi % nblkp, s0 = blk * BT;
        int pblk = (bi - 1 + nblkp) % nblkp, sp0 = pblk * BT;  // junk at bi=0
        int cb = bi & 1, pv = cb ^ 1;
        int nblk2 = (bi + 1) % nblkp, sn0 = nblk2 * BT;

        // ================= Region 1 =================
        if (wid == 0) {
            // ---- serial: 16-step chain on pre-folded gpub[pv] ----
            float g0[BT], g1[BT], vo0[BT], vo1[BT];
            #pragma unroll
            for (int u = 0; u < BT; ++u) {
                v2f gv = *(const v2f*)&gpub[pv][u * KK + 2 * kp];
                g0[u] = gv.x; g1[u] = gv.y;
                v2f vv = *(const v2f*)&V_c[(s0 + u) * KK + 2 * kp];
                vo0[u] = vv.x; vo1[u] = vv.y;
            }
            #pragma unroll
            for (int u = 0; u < BT; ++u) {
                int s = s0 + u;
                float n2 = fmaf(g0[u], g0[u], g1[u] * g1[u]);
                n2 = rowsum16(n2);
                float inv = -__builtin_amdgcn_rsqf(fmaxf(n2, 1e-16f));
                float msk = (s < nA) ? 1.f : 0.f;
                float d0 = fmaf(g0[u], inv, -vo0[u]) * msk;
                float d1 = fmaf(g1[u], inv, -vo1[u]) * msk;
                if (tid < 16) {
                    v2f dv2; dv2.x = d0; dv2.y = d1;
                    *(v2f*)&dv_s[cb][u * KK + 2 * kp] = dv2;
                    v2f vn2; vn2.x = vo0[u] + d0; vn2.y = vo1[u] + d1;
                    *(v2f*)&V_c[s * KK + 2 * kp] = vn2;
                }
                #pragma unroll
                for (int u2 = u + 1; u2 < BT; ++u2) {
                    float c = cblk_s[cb][u * BT + u2];
                    g0[u2] = fmaf(c, d0, g0[u2]);
                    g1[u2] = fmaf(c, d1, g1[u2]);
                }
            }
        } else {
            if (wid == 6) {   // cmini[u*16+t] = C[r_{s0+t}][r_{sn0+u}] = CT[sn0+u][s0+t]
                int u = l64 & 15, q = l64 >> 4;
                float4 v = *(const float4*)&CT[(size_t)(sn0 + u) * AST + s0 + 4 * q];
                *(float4*)&cmini_s[u * BT + 4 * q] = v;
            }
            if (wid == 7) {   // cblk[pv]: next block's intra tile (transposed)
                int u = l64 & 15, q = l64 >> 4;
                float4 v = *(const float4*)&CT[(size_t)(sn0 + u) * AST + sn0 + 4 * q];
                cblk_s[pv][(4 * q + 0) * BT + u] = v.x;
                cblk_s[pv][(4 * q + 1) * BT + u] = v.y;
                cblk_s[pv][(4 * q + 2) * BT + u] = v.z;
                cblk_s[pv][(4 * q + 3) * BT + u] = v.w;
            }
            // ---- bulk: rank-16 over ALL rows, two rank-8 halves ----
            if (bi > 0) {
                #pragma unroll
                for (int h = 0; h < 2; ++h) {
                    float4 dvv[8];
                    #pragma unroll
                    for (int t = 0; t < 8; ++t)
                        dvv[t] = *(const float4*)&dv_s[pv][(8 * h + t) * KK + 4 * kq];
                    float4 cA0, cB0, cA1, cB1;
                    {
                        const float* cr = CT + (size_t)rslot * AST + sp0 + 8 * h;
                        cA0 = *(const float4*)(cr);
                        cB0 = *(const float4*)(cr + 4);
                    }
                    #pragma unroll
                    for (int p = 0; p < 8; ++p) {
                        int a = rslot + 56 * p;
                        if (p < 7) {   // prefetch next pass's c
                            const float* cr = CT + (size_t)(a + 56) * AST + sp0 + 8 * h;
                            if (p & 1) { cA0 = *(const float4*)(cr); cB0 = *(const float4*)(cr + 4); }
                            else       { cA1 = *(const float4*)(cr); cB1 = *(const float4*)(cr + 4); }
                        }
                        float4 ca = (p & 1) ? cA1 : cA0;
                        float4 cbq = (p & 1) ? cB1 : cB0;
                        if (a < nAp) {
                            fma4(w[p], ca.x,  dvv[0]);
                            fma4(w[p], ca.y,  dvv[1]);
                            fma4(w[p], ca.z,  dvv[2]);
                            fma4(w[p], ca.w,  dvv[3]);
                            fma4(w[p], cbq.x, dvv[4]);
                            fma4(w[p], cbq.y, dvv[5]);
                            fma4(w[p], cbq.z, dvv[6]);
                            fma4(w[p], cbq.w, dvv[7]);
                        }
                    }
                }
                // diag self-cancel for rows of the previous block
                #pragma unroll
                for (int p = 0; p < 8; ++p) {
                    int a = rslot + 56 * p;
                    if ((a >> 4) == pblk) {
                        float4 dd = *(const float4*)&dv_s[pv][(a - sp0) * KK + 4 * kq];
                        fma4(w[p], -Cd_s[a], dd);
                    }
                }
            }
            // ---- publish next block's raw rows (fold happens in R2) ----
            #pragma unroll
            for (int p = 0; p < 8; ++p) {
                int a = rslot + 56 * p;
                if ((a >> 4) == nblk2)
                    *(float4*)&gpub[cb][(a - sn0) * KK + 4 * kq] = w[p];
            }
        }
        __syncthreads();

        // ===== Region 2: cooperative fold gpub[cb] += cmini * dv(bi) =====
        {
            int u = tid >> 5, k = tid & 31;
            float g = gpub[cb][u * KK + k];
            #pragma unroll
            for (int t = 0; t < BT; ++t)
                g = fmaf(cmini_s[u * BT + t], dv_s[cb][t * KK + k], g);
            gpub[cb][u * KK + k] = g;
        }
        __syncthreads();
    }

    // ---- epilogue: z_out ----
    int k = tid & 31, r = tid >> 5;   // r in 0..15
    float v0k = Vg[(size_t)b * NF * KK + k];
    for (int n = 1 + r; n <= NN; n += 16) {
        int ii = is_input[b * NN + n - 1];
        float res;
        if (ii == 1) {
            res = z[b * NN + n - 1];
        } else {
            int a = slot_s[n];
            float dot = V_c[a * KK + k] * v0k;
            #pragma unroll
            for (int off = 16; off; off >>= 1) dot += __shfl_xor(dot, off, 32);
            float ca = fminf(fmaxf(-dot, -1.f + 1e-6f), 1.f - 1e-6f);
            res = acosf(ca) * (1.f / PI_F);
        }
        if (k == 0) out[b * NN + n - 1] = res;
    }
}

extern "C" void kernel_launch(void* const* d_in, const int* in_sizes, int n_in,
                              void* d_out, int out_size, void* d_ws, size_t ws_size,
                              hipStream_t stream) {
    const float* coeff    = (const float*)d_in[0];
    const float* upper    = (const float*)d_in[1];
    const float* basis    = (const float*)d_in[2];
    const float* z        = (const float*)d_in[3];
    const int*   is_input = (const int*)d_in[4];
    const float* vraw     = (const float*)d_in[5];
    const int*   perm     = (const int*)d_in[6];
    float* out = (float*)d_out;

    float* ws    = (float*)d_ws;
    float* Ct    = ws;                               // 730*730
    float* V     = Ct + (size_t)NF * NF;             // 8*730*32
    float* CactT = V + (size_t)BV * NF * KK;         // 8*448*448
    float* Wc    = CactT + (size_t)BV * AST * AST;   // 8*448*32
    float* Vact  = Wc + (size_t)BV * AST * KK;       // 8*448*32
    int*   act   = (int*)(Vact + (size_t)BV * AST * KK);  // 8*448
    int*   nAa   = act + BV * AST;                   // 8
    // total ws ≈ 10.3 MB

    build_C_kernel<<<dim3((NF * NF + 255) / 256), dim3(256), 0, stream>>>(coeff, upper, basis, Ct);
    init_V_kernel<<<dim3(730), dim3(256), 0, stream>>>(z, vraw, V);
    build_act_kernel<<<dim3(BV), dim3(64), 0, stream>>>(is_input, perm, act, nAa);
    gather_CactT_kernel<<<dim3(AST, BV), dim3(256), 0, stream>>>(Ct, act, CactT);
    init_W_kernel<<<dim3(AST / 8, BV), dim3(256), 0, stream>>>(Ct, act, nAa, V, Wc, Vact);
    mix_kernel<<<dim3(BV), dim3(MTH), 0, stream>>>(CactT, Wc, Vact, act, nAa, is_input, z, V, out);
}